// Round 6
// baseline (134.001 us; speedup 1.0000x reference)
//
#include <hip/hip_runtime.h>
#include <hip/hip_bf16.h>
#include <stdint.h>

#define D_MODEL 1024
#define TOKENS  2048
#define HEADS   16
#define HDIM    64
#define NQKV    3072      // 3*D_MODEL
#define MROWS   4096      // BATCH*TOKENS

typedef __attribute__((ext_vector_type(4))) float f32x4;
typedef __attribute__((ext_vector_type(8))) short bf16x8;

__device__ __forceinline__ unsigned short f2bf(float f) {
  union { float f; unsigned u; } v; v.f = f;
  unsigned u = v.u + 0x7FFFu + ((v.u >> 16) & 1u);   // RNE
  return (unsigned short)(u >> 16);
}
__device__ __forceinline__ float bf2f(unsigned short b) {
  union { unsigned u; float f; } v; v.u = ((unsigned)b) << 16;
  return v.f;
}
__device__ __forceinline__ unsigned cvt_pk_bf16(float lo, float hi) {
  unsigned r;
  asm("v_cvt_pk_bf16_f32 %0, %1, %2" : "=v"(r) : "v"(lo), "v"(hi));
  return r;
}

#define GLOAD16(g, l)                                                          \
  __builtin_amdgcn_global_load_lds(                                            \
      (const __attribute__((address_space(1))) unsigned int*)(g),              \
      (__attribute__((address_space(3))) unsigned int*)(l), 16, 0, 0)

// ---------------------------------------------------------------------------
// fp32 -> bf16 convert pass (X then W, contiguous).
// ---------------------------------------------------------------------------
__global__ __launch_bounds__(256) void cvt_bf16(const float* __restrict__ X,
                                                const float* __restrict__ W,
                                                unsigned short* __restrict__ Xb,
                                                unsigned short* __restrict__ Wb) {
  const size_t NX = (size_t)MROWS * D_MODEL;
  size_t i = ((size_t)blockIdx.x * 256 + threadIdx.x) * 8;
  const float* src; unsigned short* dst; size_t off;
  if (i < NX) { src = X; dst = Xb; off = i; }
  else        { src = W; dst = Wb; off = i - NX; }
  float4 a = ((const float4*)(src + off))[0];
  float4 b = ((const float4*)(src + off))[1];
  union { unsigned short s[8]; uint4 v; } u;
  u.s[0] = f2bf(a.x); u.s[1] = f2bf(a.y); u.s[2] = f2bf(a.z); u.s[3] = f2bf(a.w);
  u.s[4] = f2bf(b.x); u.s[5] = f2bf(b.y); u.s[6] = f2bf(b.z); u.s[7] = f2bf(b.w);
  *(uint4*)(dst + off) = u.v;
}

// ---------------------------------------------------------------------------
// bf16 GEMM (m97 structure): 128x128 tile, BK=64, global_load_lds width=16.
// ---------------------------------------------------------------------------
__global__ __launch_bounds__(256) void gemm_bf16(const unsigned short* __restrict__ A,
                                                 const unsigned short* __restrict__ B,
                                                 unsigned short* __restrict__ C) {
  __shared__ unsigned short sA[128 * 64];
  __shared__ unsigned short sB[128 * 64];
  const int tid  = threadIdx.x;
  const int lane = tid & 63;
  const int wave = tid >> 6;
  const int wr = wave >> 1, wc = wave & 1;
  const int row0 = blockIdx.x * 128;
  const int col0 = blockIdx.y * 128;

  f32x4 acc[4][4];
#pragma unroll
  for (int i = 0; i < 4; ++i)
#pragma unroll
    for (int j = 0; j < 4; ++j)
#pragma unroll
      for (int r = 0; r < 4; ++r) acc[i][j][r] = 0.f;

  const int lrow = lane & 15;
  const int lg   = lane >> 4;
  const int strow = (lane >> 3);
  const int stcol = (lane & 7) * 8;

#pragma unroll 1
  for (int k0 = 0; k0 < D_MODEL; k0 += 64) {
#pragma unroll
    for (int i = 0; i < 4; ++i) {
      const int r = wave * 32 + i * 8 + strow;
      GLOAD16(A + (size_t)(row0 + r) * D_MODEL + k0 + stcol, &sA[r * 64 + stcol]);
      GLOAD16(B + (size_t)(col0 + r) * D_MODEL + k0 + stcol, &sB[r * 64 + stcol]);
    }
    __syncthreads();

    bf16x8 av[4][2], bv[4][2];
#pragma unroll
    for (int c = 0; c < 2; ++c) {
#pragma unroll
      for (int i = 0; i < 4; ++i)
        av[i][c] = *(const bf16x8*)&sA[(wr * 64 + i * 16 + lrow) * 64 + c * 32 + lg * 8];
#pragma unroll
      for (int j = 0; j < 4; ++j)
        bv[j][c] = *(const bf16x8*)&sB[(wc * 64 + j * 16 + lrow) * 64 + c * 32 + lg * 8];
    }
#pragma unroll
    for (int c = 0; c < 2; ++c)
#pragma unroll
      for (int i = 0; i < 4; ++i)
#pragma unroll
        for (int j = 0; j < 4; ++j)
          acc[i][j] = __builtin_amdgcn_mfma_f32_16x16x32_bf16(av[i][c], bv[j][c], acc[i][j], 0, 0, 0);
    __syncthreads();
  }

  const int orow = row0 + wr * 64 + (lane >> 4) * 4;
  const int ocol = col0 + wc * 64 + (lane & 15);
#pragma unroll
  for (int i = 0; i < 4; ++i)
#pragma unroll
    for (int j = 0; j < 4; ++j)
#pragma unroll
      for (int r = 0; r < 4; ++r)
        C[(size_t)(orow + i * 16 + r) * NQKV + ocol + j * 16] = f2bf(acc[i][j][r]);
}

// ---------------------------------------------------------------------------
// Fallback fp32-input GEMM for small ws.
// ---------------------------------------------------------------------------
__global__ __launch_bounds__(256) void qkv_gemm(const float* __restrict__ X,
                                                const float* __restrict__ W,
                                                unsigned short* __restrict__ QKV) {
  __shared__ unsigned short sA[128 * 32];
  __shared__ unsigned short sB[128 * 32];
  const int tid  = threadIdx.x;
  const int lane = tid & 63;
  const int wave = tid >> 6;
  const int wr = wave >> 1, wc = wave & 1;
  const int row0 = blockIdx.x * 128;
  const int col0 = blockIdx.y * 128;

  f32x4 acc[4][4];
#pragma unroll
  for (int i = 0; i < 4; ++i)
#pragma unroll
    for (int j = 0; j < 4; ++j)
#pragma unroll
      for (int r = 0; r < 4; ++r) acc[i][j][r] = 0.f;

  const int srow = tid >> 1;
  const int scol = (tid & 1) * 16;
  union U16 { unsigned short s[8]; uint4 v; };

#pragma unroll 1
  for (int k0 = 0; k0 < D_MODEL; k0 += 32) {
    {
      const float* ga = X + (size_t)(row0 + srow) * D_MODEL + k0 + scol;
      const float* gb = W + (size_t)(col0 + srow) * D_MODEL + k0 + scol;
      float va[16], vb[16];
#pragma unroll
      for (int i = 0; i < 4; ++i) {
        float4 t = ((const float4*)ga)[i];
        va[4*i+0] = t.x; va[4*i+1] = t.y; va[4*i+2] = t.z; va[4*i+3] = t.w;
        float4 u = ((const float4*)gb)[i];
        vb[4*i+0] = u.x; vb[4*i+1] = u.y; vb[4*i+2] = u.z; vb[4*i+3] = u.w;
      }
      U16 ua0, ua1, ub0, ub1;
#pragma unroll
      for (int e = 0; e < 8; ++e) {
        ua0.s[e] = f2bf(va[e]);   ua1.s[e] = f2bf(va[8 + e]);
        ub0.s[e] = f2bf(vb[e]);   ub1.s[e] = f2bf(vb[8 + e]);
      }
      *(uint4*)&sA[srow * 32 + scol + 0] = ua0.v;
      *(uint4*)&sA[srow * 32 + scol + 8] = ua1.v;
      *(uint4*)&sB[srow * 32 + scol + 0] = ub0.v;
      *(uint4*)&sB[srow * 32 + scol + 8] = ub1.v;
    }
    __syncthreads();

    const int lrow = lane & 15;
    const int lk   = (lane >> 4) * 8;
    bf16x8 av[4], bv[4];
#pragma unroll
    for (int i = 0; i < 4; ++i)
      av[i] = *(const bf16x8*)&sA[(wr * 64 + i * 16 + lrow) * 32 + lk];
#pragma unroll
    for (int j = 0; j < 4; ++j)
      bv[j] = *(const bf16x8*)&sB[(wc * 64 + j * 16 + lrow) * 32 + lk];
#pragma unroll
    for (int i = 0; i < 4; ++i)
#pragma unroll
      for (int j = 0; j < 4; ++j)
        acc[i][j] = __builtin_amdgcn_mfma_f32_16x16x32_bf16(av[i], bv[j], acc[i][j], 0, 0, 0);
    __syncthreads();
  }

  const int orow = row0 + wr * 64 + (lane >> 4) * 4;
  const int ocol = col0 + wc * 64 + (lane & 15);
#pragma unroll
  for (int i = 0; i < 4; ++i)
#pragma unroll
    for (int j = 0; j < 4; ++j)
#pragma unroll
      for (int r = 0; r < 4; ++r)
        QKV[(size_t)(orow + i * 16 + r) * NQKV + ocol + j * 16] = f2bf(acc[i][j][r]);
}

// ---------------------------------------------------------------------------
// Shared attention machinery: swapped QK^T + lane-local softmax + swapped PV.
// ---------------------------------------------------------------------------
struct Strip {
  bf16x8 qf[2];
  f32x4  o[4];    // o[db][r] = O[dim = db*16 + lg*4 + r][q = l15]
  float  m, l;    // per-lane (q = l15), identical across lg groups
};

__device__ __forceinline__ void strip_step(Strip& S, const char* cK, const char* cVt,
                                           char* cP, int l15, int lg, int kbase,
                                           int qcol, bool diag) {
  f32x4 st[4];
#pragma unroll
  for (int f = 0; f < 4; ++f)
#pragma unroll
    for (int r = 0; r < 4; ++r) st[f][r] = 0.f;

  __builtin_amdgcn_s_setprio(1);
#pragma unroll
  for (int c = 0; c < 2; ++c) {
#pragma unroll
    for (int f = 0; f < 4; ++f) {
      const int key = f * 16 + l15;
      const int off = (key * 128 + (c * 32 + lg * 8) * 2) ^ ((l15 & 7) << 4);
      bf16x8 kf = *(const bf16x8*)(cK + off);
      st[f] = __builtin_amdgcn_mfma_f32_16x16x32_bf16(kf, S.qf[c], st[f], 0, 0, 0);
    }
  }
  __builtin_amdgcn_s_setprio(0);

  if (diag) {
#pragma unroll
    for (int f = 0; f < 4; ++f) {
#pragma unroll
      for (int r = 0; r < 4; ++r) {
        const int kg = kbase + f * 16 + lg * 4 + r;
        if (kg > qcol) st[f][r] = -1e30f;
      }
    }
  }

  float a0 = fmaxf(st[0][0], st[0][1]), a1 = fmaxf(st[0][2], st[0][3]);
  float a2 = fmaxf(st[1][0], st[1][1]), a3 = fmaxf(st[1][2], st[1][3]);
  float a4 = fmaxf(st[2][0], st[2][1]), a5 = fmaxf(st[2][2], st[2][3]);
  float a6 = fmaxf(st[3][0], st[3][1]), a7 = fmaxf(st[3][2], st[3][3]);
  float b0 = fmaxf(a0, a1), b1 = fmaxf(a2, a3), b2 = fmaxf(a4, a5), b3 = fmaxf(a6, a7);
  float mx = fmaxf(fmaxf(b0, b1), fmaxf(b2, b3));
  mx = fmaxf(mx, __shfl_xor(mx, 16));
  mx = fmaxf(mx, __shfl_xor(mx, 32));

  if (!__all(mx - S.m <= 8.f)) {
    const float mnew = fmaxf(S.m, mx);
    const float corr = exp2f(S.m - mnew);
    S.m = mnew;
    S.l *= corr;
#pragma unroll
    for (int db = 0; db < 4; ++db)
#pragma unroll
      for (int r = 0; r < 4; ++r) S.o[db][r] *= corr;
  }

  float p[4][4];
#pragma unroll
  for (int f = 0; f < 4; ++f)
#pragma unroll
    for (int r = 0; r < 4; ++r) p[f][r] = exp2f(st[f][r] - S.m);
  float s0 = (p[0][0] + p[0][1]) + (p[0][2] + p[0][3]);
  float s1 = (p[1][0] + p[1][1]) + (p[1][2] + p[1][3]);
  float s2 = (p[2][0] + p[2][1]) + (p[2][2] + p[2][3]);
  float s3 = (p[3][0] + p[3][1]) + (p[3][2] + p[3][3]);
  float ps = (s0 + s1) + (s2 + s3);
  ps += __shfl_xor(ps, 16);
  ps += __shfl_xor(ps, 32);
  S.l += ps;

#pragma unroll
  for (int f = 0; f < 4; ++f) {
    uint2 w;
    w.x = cvt_pk_bf16(p[f][0], p[f][1]);
    w.y = cvt_pk_bf16(p[f][2], p[f][3]);
    *(uint2*)(cP + ((l15 * 128 + (f * 16 + lg * 4) * 2) ^ ((l15 & 7) << 4))) = w;
  }

  __builtin_amdgcn_s_setprio(1);
#pragma unroll
  for (int c = 0; c < 2; ++c) {
    bf16x8 pa = *(const bf16x8*)(cP + ((l15 * 128 + (c * 32 + lg * 8) * 2) ^ ((l15 & 7) << 4)));
#pragma unroll
    for (int db = 0; db < 4; ++db) {
      const int dim = db * 16 + l15;
      const int boff = (dim * 128 + (c * 32 + lg * 8) * 2) ^ ((l15 & 7) << 4);
      bf16x8 vb = *(const bf16x8*)(cVt + boff);
      S.o[db] = __builtin_amdgcn_mfma_f32_16x16x32_bf16(vb, pa, S.o[db], 0, 0, 0);
    }
  }
  __builtin_amdgcn_s_setprio(0);
}

#define LOAD_KV(kt)                                                            \
  {                                                                            \
    const unsigned short* ks = Kbase + (size_t)((kt) * 64 + skey) * NQKV + sd0;\
    ka  = ((const uint4*)ks)[0];                                               \
    kb2 = ((const uint4*)ks)[1];                                               \
    const unsigned short* vs = Vbase + (size_t)((kt) * 64 + vk0) * NQKV + vd0; \
    v0 = *(const ushort4*)(vs);                                                \
    v1 = *(const ushort4*)(vs + NQKV);                                         \
    v2 = *(const ushort4*)(vs + 2 * NQKV);                                     \
    v3 = *(const ushort4*)(vs + 3 * NQKV);                                     \
  }

#define WRITE_KV(buf)                                                          \
  {                                                                            \
    char* dK = (char*)&sK[(buf)][0];                                           \
    const int off = skey * 128 + sd0 * 2;                                      \
    const int sw  = (skey & 7) << 4;                                           \
    *(uint4*)(dK + ((off) ^ sw))      = ka;                                    \
    *(uint4*)(dK + ((off + 16) ^ sw)) = kb2;                                   \
    ushort4 c0, c1, c2, c3;                                                    \
    c0.x = v0.x; c0.y = v1.x; c0.z = v2.x; c0.w = v3.x;                        \
    c1.x = v0.y; c1.y = v1.y; c1.z = v2.y; c1.w = v3.y;                        \
    c2.x = v0.z; c2.y = v1.z; c2.z = v2.z; c2.w = v3.z;                        \
    c3.x = v0.w; c3.y = v1.w; c3.z = v2.w; c3.w = v3.w;                        \
    char* dV = (char*)&sVt[(buf)][0];                                          \
    _Pragma("unroll")                                                          \
    for (int e = 0; e < 4; ++e) {                                              \
      const int dim = vd0 + e;                                                 \
      const int o2 = (dim * 128 + vk0 * 2) ^ ((dim & 7) << 4);                 \
      ushort4 cc = (e == 0) ? c0 : (e == 1) ? c1 : (e == 2) ? c2 : c3;         \
      *(ushort4*)(dV + o2) = cc;                                               \
    }                                                                          \
  }

// ---------------------------------------------------------------------------
// K-split flash attention: block = (bh, qt, split s of nc). nc = ceil((qt+1)/8).
// Tiles t = s, s+nc, ... <= qt (strided; online softmax is order-independent).
// nc==1 writes Out directly; else writes unnormalized partial (O bf16, m/l f32).
// 2560 blocks -> ~4 blocks/CU resident (LDS 40KB).
// ---------------------------------------------------------------------------
__global__ __launch_bounds__(256) void attn_split(const unsigned short* __restrict__ QKV,
                                                  float* __restrict__ Out,
                                                  unsigned short* __restrict__ Opart,
                                                  float* __restrict__ ML) {
  __shared__ unsigned short sK [2][64 * 64];
  __shared__ unsigned short sVt[2][64 * 64];
  __shared__ unsigned short sP [4][16 * 64];

  const int tid  = threadIdx.x;
  const int lane = tid & 63;
  const int wave = tid >> 6;
  const int l15  = lane & 15;
  const int lg   = lane >> 4;

  const int e  = blockIdx.x;            // 0..79
  int qt, s, nc, slot;
  if (e < 8)       { qt = e;                    s = 0;      nc = 1; slot = qt; }
  else if (e < 24) { int u = e - 8;  qt = 8  + (u >> 1); s = u & 1; nc = 2; slot = 8  + (qt - 8)  * 2 + s; }
  else if (e < 48) { int u = e - 24; qt = 16 + u / 3;    s = u % 3; nc = 3; slot = 24 + (qt - 16) * 3 + s; }
  else             { int u = e - 48; qt = 24 + (u >> 2); s = u & 3; nc = 4; slot = 48 + (qt - 24) * 4 + s; }

  const int bh = blockIdx.y;
  const int b = bh >> 4, h = bh & 15;
  const int q0 = qt * 64;

  const unsigned short* Qbase = QKV + (size_t)(b * TOKENS) * NQKV + h * HDIM;
  const unsigned short* Kbase = Qbase + D_MODEL;
  const unsigned short* Vbase = Kbase + D_MODEL;

  Strip S;
#pragma unroll
  for (int db = 0; db < 4; ++db)
#pragma unroll
    for (int r = 0; r < 4; ++r) S.o[db][r] = 0.f;
  S.m = -1e30f; S.l = 0.f;
  {
    union { unsigned short us[8]; bf16x8 v; ushort4 u[2]; } tmp;
#pragma unroll
    for (int c = 0; c < 2; ++c) {
      const unsigned short* p = Qbase + (size_t)(q0 + wave * 16 + l15) * NQKV + c * 32 + lg * 8;
      tmp.u[0] = ((const ushort4*)p)[0]; tmp.u[1] = ((const ushort4*)p)[1];
#pragma unroll
      for (int ee = 0; ee < 8; ++ee) tmp.us[ee] = f2bf(bf2f(tmp.us[ee]) * 0.18033688011112042f);
      S.qf[c] = tmp.v;
    }
  }
  const int qcol = q0 + wave * 16 + l15;

  const int skey = tid >> 2;
  const int sd0  = (tid & 3) * 16;
  const int vk0  = (tid & 15) * 4;
  const int vd0  = (tid >> 4) * 4;

  uint4 ka, kb2;
  ushort4 v0, v1, v2, v3;

  LOAD_KV(s);
  WRITE_KV(0);
  __syncthreads();

  char* const cP = (char*)&sP[wave][0];

  int step = 0;
#pragma unroll 1
  for (int t = s; t <= qt; t += nc, ++step) {
    const int cur = step & 1;
    const bool more = (t + nc <= qt);
    if (more) LOAD_KV(t + nc);

    strip_step(S, (const char*)&sK[cur][0], (const char*)&sVt[cur][0],
               cP, l15, lg, t * 64, qcol, t == qt);

    if (more) WRITE_KV((step + 1) & 1);
    __syncthreads();
  }

  if (nc == 1) {
    const float inv = 1.f / S.l;
    const int q = q0 + wave * 16 + l15;
    float* orow = Out + (size_t)(b * TOKENS + q) * D_MODEL + h * HDIM;
#pragma unroll
    for (int db = 0; db < 4; ++db)
#pragma unroll
      for (int r = 0; r < 4; ++r)
        orow[db * 16 + lg * 4 + r] = S.o[db][r] * inv;
  } else {
    unsigned short* ob = Opart + ((size_t)(bh * 80 + slot)) * 4096 + (wave * 16 + l15) * 64;
#pragma unroll
    for (int db = 0; db < 4; ++db) {
      uint2 w;
      w.x = cvt_pk_bf16(S.o[db][0], S.o[db][1]);
      w.y = cvt_pk_bf16(S.o[db][2], S.o[db][3]);
      *(uint2*)(ob + db * 16 + lg * 4) = w;
    }
    if (lg == 0) {
      float2* mlrow = (float2*)ML + ((size_t)(bh * 80 + slot)) * 64 + wave * 16 + l15;
      float2 t2; t2.x = S.m; t2.y = S.l;
      *mlrow = t2;
    }
  }
}

// ---------------------------------------------------------------------------
// Merge: combine nc partials per (bh, qt>=8, q). 256 thr: q=tid>>2, 16 dims.
// ---------------------------------------------------------------------------
__global__ __launch_bounds__(256) void merge_split(const unsigned short* __restrict__ Opart,
                                                   const float* __restrict__ ML,
                                                   float* __restrict__ Out) {
  const int qt = 8 + blockIdx.x;        // 8..31
  const int bh = blockIdx.y;
  const int b = bh >> 4, h = bh & 15;
  int nc, slot0;
  if (qt < 16)      { nc = 2; slot0 = 8  + (qt - 8)  * 2; }
  else if (qt < 24) { nc = 3; slot0 = 24 + (qt - 16) * 3; }
  else              { nc = 4; slot0 = 48 + (qt - 24) * 4; }

  const int q  = threadIdx.x >> 2;      // 0..63
  const int d0 = (threadIdx.x & 3) * 16;

  float m[4], l[4];
  float M = -1e30f;
#pragma unroll 1
  for (int si = 0; si < nc; ++si) {
    float2 t = ((const float2*)ML)[((size_t)(bh * 80 + slot0 + si)) * 64 + q];
    m[si] = t.x; l[si] = t.y;
    M = fmaxf(M, t.x);
  }
  float L = 0.f, w[4];
#pragma unroll 1
  for (int si = 0; si < nc; ++si) { w[si] = exp2f(m[si] - M); L += l[si] * w[si]; }
  const float invL = 1.f / L;

  float acc[16];
#pragma unroll
  for (int i = 0; i < 16; ++i) acc[i] = 0.f;
#pragma unroll 1
  for (int si = 0; si < nc; ++si) {
    const unsigned short* ob = Opart + ((size_t)(bh * 80 + slot0 + si)) * 4096 + q * 64 + d0;
    ushort4 u0 = ((const ushort4*)ob)[0];
    ushort4 u1 = ((const ushort4*)ob)[1];
    ushort4 u2 = ((const ushort4*)ob)[2];
    ushort4 u3 = ((const ushort4*)ob)[3];
    const float ws = w[si];
    acc[0]  += bf2f(u0.x) * ws; acc[1]  += bf2f(u0.y) * ws;
    acc[2]  += bf2f(u0.z) * ws; acc[3]  += bf2f(u0.w) * ws;
    acc[4]  += bf2f(u1.x) * ws; acc[5]  += bf2f(u1.y) * ws;
    acc[6]  += bf2f(u1.z) * ws; acc[7]  += bf2f(u1.w) * ws;
    acc[8]  += bf2f(u2.x) * ws; acc[9]  += bf2f(u2.y) * ws;
    acc[10] += bf2f(u2.z) * ws; acc[11] += bf2f(u2.w) * ws;
    acc[12] += bf2f(u3.x) * ws; acc[13] += bf2f(u3.y) * ws;
    acc[14] += bf2f(u3.z) * ws; acc[15] += bf2f(u3.w) * ws;
  }
  float* orow = Out + (size_t)(b * TOKENS + qt * 64 + q) * D_MODEL + h * HDIM + d0;
#pragma unroll
  for (int i = 0; i < 4; ++i) {
    float4 o;
    o.x = acc[4*i+0] * invL; o.y = acc[4*i+1] * invL;
    o.z = acc[4*i+2] * invL; o.w = acc[4*i+3] * invL;
    ((float4*)orow)[i] = o;
  }
}

// ---------------------------------------------------------------------------
// Fallback attention (round-5 verified): pair-balanced, no K-split.
// ---------------------------------------------------------------------------
__global__ __launch_bounds__(256) void attn3(const unsigned short* __restrict__ QKV,
                                             float* __restrict__ Out) {
  __shared__ unsigned short sK [2][64 * 64];
  __shared__ unsigned short sVt[2][64 * 64];
  __shared__ unsigned short sP [4][16 * 64];

  const int tid  = threadIdx.x;
  const int lane = tid & 63;
  const int wave = tid >> 6;
  const int l15  = lane & 15;
  const int lg   = lane >> 4;
  const int pidx = blockIdx.x;
  const int bh = blockIdx.y;
  const int b = bh >> 4, h = bh & 15;

  const int qtl = pidx, qth = 31 - pidx;
  const int q0l = qtl * 64, q0h = qth * 64;
  const int nstage = qth + 1;

  const unsigned short* Qbase = QKV + (size_t)(b * TOKENS) * NQKV + h * HDIM;
  const unsigned short* Kbase = Qbase + D_MODEL;
  const unsigned short* Vbase = Kbase + D_MODEL;

  Strip SL, SH;
#pragma unroll
  for (int db = 0; db < 4; ++db)
#pragma unroll
    for (int r = 0; r < 4; ++r) { SL.o[db][r] = 0.f; SH.o[db][r] = 0.f; }
  SL.m = -1e30f; SL.l = 0.f; SH.m = -1e30f; SH.l = 0.f;
  {
    union { unsigned short us[8]; bf16x8 v; ushort4 u[2]; } tmp;
#pragma unroll
    for (int c = 0; c < 2; ++c) {
      const unsigned short* pl = Qbase + (size_t)(q0l + wave * 16 + l15) * NQKV + c * 32 + lg * 8;
      tmp.u[0] = ((const ushort4*)pl)[0]; tmp.u[1] = ((const ushort4*)pl)[1];
#pragma unroll
      for (int ee = 0; ee < 8; ++ee) tmp.us[ee] = f2bf(bf2f(tmp.us[ee]) * 0.18033688011112042f);
      SL.qf[c] = tmp.v;
      const unsigned short* ph = Qbase + (size_t)(q0h + wave * 16 + l15) * NQKV + c * 32 + lg * 8;
      tmp.u[0] = ((const ushort4*)ph)[0]; tmp.u[1] = ((const ushort4*)ph)[1];
#pragma unroll
      for (int ee = 0; ee < 8; ++ee) tmp.us[ee] = f2bf(bf2f(tmp.us[ee]) * 0.18033688011112042f);
      SH.qf[c] = tmp.v;
    }
  }
  const int qcolL = q0l + wave * 16 + l15;
  const int qcolH = q0h + wave * 16 + l15;

  const int skey = tid >> 2;
  const int sd0  = (tid & 3) * 16;
  const int vk0  = (tid & 15) * 4;
  const int vd0  = (tid >> 4) * 4;

  uint4 ka, kb2;
  ushort4 v0, v1, v2, v3;

  LOAD_KV(0);
  WRITE_KV(0);
  __syncthreads();

  char* const cP = (char*)&sP[wave][0];

#pragma unroll 1
  for (int kt = 0; kt < nstage; ++kt) {
    const int cur = kt & 1;
    if (kt + 1 < nstage) LOAD_KV(kt + 1);

    const char* cK  = (const char*)&sK[cur][0];
    const char* cVt = (const char*)&sVt[cur][0];
    const int kbase = kt * 64;

    strip_step(SH, cK, cVt, cP, l15, lg, kbase, qcolH, kt == qth);
    if (kt <= qtl)
      strip_step(SL, cK, cVt, cP, l15, lg, kbase, qcolL, kt == qtl);

    if (kt + 1 < nstage) WRITE_KV((kt + 1) & 1);
    __syncthreads();
  }

  {
    const float ih = 1.f / SH.l;
    const float il = 1.f / SL.l;
    const int qh = q0h + wave * 16 + l15;
    const int ql = q0l + wave * 16 + l15;
    float* oh = Out + (size_t)(b * TOKENS + qh) * D_MODEL + h * HDIM;
    float* ol = Out + (size_t)(b * TOKENS + ql) * D_MODEL + h * HDIM;
#pragma unroll
    for (int db = 0; db < 4; ++db)
#pragma unroll
      for (int r = 0; r < 4; ++r) {
        oh[db * 16 + lg * 4 + r] = SH.o[db][r] * ih;
        ol[db * 16 + lg * 4 + r] = SL.o[db][r] * il;
      }
  }
}

extern "C" void kernel_launch(void* const* d_in, const int* in_sizes, int n_in,
                              void* d_out, int out_size, void* d_ws, size_t ws_size,
                              hipStream_t stream) {
  const float* X = (const float*)d_in[0];
  const float* W = (const float*)d_in[1];
  float* Out = (float*)d_out;
  unsigned short* QKV = (unsigned short*)d_ws;

  const size_t QKV_E   = (size_t)MROWS * NQKV;        // 12.58M shorts
  const size_t XB_E    = (size_t)MROWS * D_MODEL;     // 4.19M
  const size_t WB_E    = (size_t)NQKV * D_MODEL;      // 3.15M
  const size_t OPART_E = (size_t)32 * 80 * 4096;      // 10.49M shorts
  const size_t ML_B    = (size_t)32 * 80 * 64 * 2 * sizeof(float);  // 1.31MB

  const size_t need_bf16  = (QKV_E + XB_E + WB_E) * 2;
  const size_t need_split = need_bf16 + OPART_E * 2 + ML_B;

  const bool have_bf16  = ws_size >= need_bf16;
  const bool have_split = ws_size >= need_split;

  if (have_bf16) {
    unsigned short* Xb = QKV + QKV_E;
    unsigned short* Wb = Xb + XB_E;
    cvt_bf16<<<(XB_E + WB_E) / (256 * 8), 256, 0, stream>>>(X, W, Xb, Wb);
    gemm_bf16<<<dim3(MROWS / 128, NQKV / 128), 256, 0, stream>>>(Xb, Wb, QKV);
  } else {
    qkv_gemm<<<dim3(MROWS / 128, NQKV / 128), 256, 0, stream>>>(X, W, QKV);
  }

  if (have_split) {
    unsigned short* Opart = QKV + QKV_E + XB_E + WB_E;
    float* ML = (float*)(Opart + OPART_E);
    attn_split<<<dim3(80, 2 * HEADS), 256, 0, stream>>>(QKV, Out, Opart, ML);
    merge_split<<<dim3(24, 2 * HEADS), 256, 0, stream>>>(Opart, ML, Out);
  } else {
    attn3<<<dim3(16, 2 * HEADS), 256, 0, stream>>>(QKV, Out);
  }
}